// Round 4
// baseline (587.444 us; speedup 1.0000x reference)
//
#include <hip/hip_runtime.h>
#include <hip/hip_bf16.h>

typedef __attribute__((ext_vector_type(8))) short short8v;
typedef __attribute__((ext_vector_type(4))) float f32x4;

#define IMG 256
#define NIMG 16
#define XB_ELEMS (NIMG * IMG * IMG)

// packed-weight element offsets: per sigma stride = K*NSV*512 elems, 8 sigmas
#define WQ0 0u
#define WQ1 102400u        // + 8*25*1*512
#define WQ2 503808u        // + 8*49*2*512
#define WQ3 2093056u       // + 8*97*4*512
#define WQEND 7624704u     // + 8*193*7*512   (15.25 MB)

#define BUFB 16384         // one LDS buffer: 32 rows x 512 B

__global__ void xconvert_kernel(const float* __restrict__ x,
                                __hip_bfloat16* __restrict__ xb) {
  int i = blockIdx.x * blockDim.x + threadIdx.x;
  if (i < XB_ELEMS) xb[i] = __float2bfloat16(x[i]);
}

// wq[sig][u][sv][lane*8+e]; u in [0,K) (no u-padding), v = 32sv+8(lane>>4)+e - sig
__global__ void wpack_kernel(const float* __restrict__ w,
                             unsigned short* __restrict__ wq,
                             int K, int NSV, int total) {
  for (int idx = blockIdx.x * blockDim.x + threadIdx.x; idx < total;
       idx += gridDim.x * blockDim.x) {
    int e = idx & 7, lane = (idx >> 3) & 63, rest = idx >> 9;
    int sv = rest % NSV; rest /= NSV;
    int u = rest % K, sig = rest / K;
    int o = lane & 15;
    int v = sv * 32 + (lane >> 4) * 8 + e - sig;
    float val = (v >= 0 && v < K) ? w[(o * K + u) * K + v] : 0.0f;
    __hip_bfloat16 h = __float2bfloat16(val);
    wq[idx] = *(unsigned short*)&h;
  }
}

// Inner body: compile-time g-mask (bit0 = row-group 0, bit1 = row-group 1).
template <int GM, int NSV, int JBA>
__device__ __forceinline__ void kbody(int c, int rb0, int rb1, const char* bufc,
                                      const unsigned short* __restrict__ Wa,
                                      const unsigned short* __restrict__ Wb,
                                      int cbBase, int lr, f32x4 (&acc)[2][2][JBA]) {
#pragma unroll 1
  for (int rbL = rb0; rbL < rb1; ++rbL) {
    const int rowLoc = rbL + lr;
    const char* rbase = bufc + rowLoc * 512;
    const int u0i = 16 * c + rbL;                 // u for g=0; g=1 uses u0i-16
#pragma unroll
    for (int sv = 0; sv < NSV; ++sv) {
      short8v a_[JBA];
#pragma unroll
      for (int jb = 0; jb < JBA; ++jb) {
        int cb = cbBase + 16 * jb + 64 * sv;
        int addr = (cb & ~127) + ((((cb >> 4) ^ rowLoc) & 7) << 4);
        a_[jb] = *(const short8v*)(rbase + addr);
      }
      if (GM & 1) {
        const int wo = (u0i * NSV + sv) * 512;
        short8v ba = *(const short8v*)(Wa + wo);
        short8v bb = *(const short8v*)(Wb + wo);
#pragma unroll
        for (int jb = 0; jb < JBA; ++jb) {
          acc[0][0][jb] = __builtin_amdgcn_mfma_f32_16x16x32_bf16(a_[jb], ba, acc[0][0][jb], 0, 0, 0);
          acc[0][1][jb] = __builtin_amdgcn_mfma_f32_16x16x32_bf16(a_[jb], bb, acc[0][1][jb], 0, 0, 0);
        }
      }
      if (GM & 2) {
        const int wo = ((u0i - 16) * NSV + sv) * 512;
        short8v ba = *(const short8v*)(Wa + wo);
        short8v bb = *(const short8v*)(Wb + wo);
#pragma unroll
        for (int jb = 0; jb < JBA; ++jb) {
          acc[1][0][jb] = __builtin_amdgcn_mfma_f32_16x16x32_bf16(a_[jb], ba, acc[1][0][jb], 0, 0, 0);
          acc[1][1][jb] = __builtin_amdgcn_mfma_f32_16x16x32_bf16(a_[jb], bb, acc[1][1][jb], 0, 0, 0);
        }
      }
    }
  }
}

// Per-scale conv+energy. G=2 row-groups, JSIG=2 sigmas per block (sigma pair q),
// WC compute waves (JBA t-slots each), 8-WC producer waves do all LDS staging.
template <int KL, int KFULL, int NSV, int JBA, int WC, int HOUT, int SIDX>
__device__ __forceinline__ void conv_scale(const unsigned short* __restrict__ xb,
                                           const unsigned short* __restrict__ wq_s,
                                           float* __restrict__ E, char* lds,
                                           int n, int i0, int u0, int q) {
  constexpr int M16 = KL >> 4, R = KL & 15;
  constexpr int NCH = M16 + (R ? 2 : 1);
  constexpr unsigned SSTRIDE = (unsigned)KFULL * NSV * 512;

  const int wv = threadIdx.x >> 6, lane = threadIdx.x & 63;
  const int lr = lane & 15, lg = lane >> 4;
  const bool isProd = (WC < 8) && (wv >= WC);
  const unsigned short* Xn = xb + ((unsigned)n << 16);
  const int rowG0 = i0 + u0;

  const unsigned short* Wa = wq_s + (unsigned)(2 * q) * SSTRIDE +
                             (unsigned)(u0 * NSV) * 512 + lane * 8;
  const unsigned short* Wb = Wa + SSTRIDE;

  // Stage 32 rows (16 KB, 16x 1KB loads) of chunk cn into buffer cn&1.
  // LDS dest linear; source col pre-swizzled: slot' = (slot&~7)|((slot^row)&7).
  auto stage = [&](int cn) {
    char* dst = lds + (cn & 1) * BUFB;
    constexpr int NSTG = (WC < 8) ? (8 - WC) : 8;
    const int sid = (WC < 8) ? (wv - WC) : wv;
    constexpr int M = (16 + NSTG - 1) / NSTG;
#pragma unroll
    for (int k2 = 0; k2 < M; ++k2) {
      int ib = sid + NSTG * k2;
      if (ib >= 16) ib = 0;                       // benign duplicate
      int P = ib * 1024 + lane * 16;
      int lrow = P >> 9;
      int slot = (P >> 4) & 31;
      int srcslot = (slot & ~7) | ((slot ^ lrow) & 7);
      int grow = rowG0 + cn * 16 + lrow;
      if (grow > 255) grow = 255;
      const unsigned short* gp = Xn + (grow << 8) + srcslot * 8;
      __builtin_amdgcn_global_load_lds(
          (const __attribute__((address_space(1))) unsigned int*)(const void*)gp,
          (__attribute__((address_space(3))) unsigned int*)(void*)(dst + P), 16, 0, 0);
    }
  };

  if (isProd) {
    stage(0);
    asm volatile("s_waitcnt vmcnt(0)" ::: "memory");
    __builtin_amdgcn_s_barrier();
    for (int c = 0; c < NCH; ++c) {
      if (c + 1 < NCH) {
        stage(c + 1);
        asm volatile("s_waitcnt vmcnt(0)" ::: "memory");
      }
      __builtin_amdgcn_s_barrier();
    }
    return;
  }

  f32x4 acc[2][2][JBA];
#pragma unroll
  for (int g = 0; g < 2; ++g)
#pragma unroll
    for (int sj = 0; sj < 2; ++sj)
#pragma unroll
      for (int jb = 0; jb < JBA; ++jb) acc[g][sj][jb] = (f32x4)(0.0f);

  const int t0 = wv * JBA;
  const int cbBase = 16 * t0 + 16 * lg;

  if (WC == 8) {                                   // no producers: stage ourselves
    stage(0);
    asm volatile("s_waitcnt vmcnt(0)" ::: "memory");
  }
  __builtin_amdgcn_s_barrier();

#define STEP_PRE(c)  if (WC == 8 && (c) + 1 < NCH) stage((c) + 1);
#define STEP_POST()  if (WC == 8) asm volatile("s_waitcnt vmcnt(0)" ::: "memory"); \
                     __builtin_amdgcn_s_barrier();

  {  // step 0: g0 only, full
    const char* bufc = lds;
    STEP_PRE(0)
    kbody<1, NSV, JBA>(0, 0, 16, bufc, Wa, Wb, cbBase, lr, acc);
    STEP_POST()
  }
#pragma unroll 1
  for (int c = 1; c < M16; ++c) {                  // steady: both groups
    const char* bufc = lds + (c & 1) * BUFB;
    STEP_PRE(c)
    kbody<3, NSV, JBA>(c, 0, 16, bufc, Wa, Wb, cbBase, lr, acc);
    STEP_POST()
  }
  if (R > 0) {
    {  // step M16: g0 partial (rbL<R), g1 full
      const char* bufc = lds + (M16 & 1) * BUFB;
      STEP_PRE(M16)
      kbody<3, NSV, JBA>(M16, 0, R, bufc, Wa, Wb, cbBase, lr, acc);
      kbody<2, NSV, JBA>(M16, R, 16, bufc, Wa, Wb, cbBase, lr, acc);
      STEP_POST()
    }
    {  // step M16+1: g1 partial
      const char* bufc = lds + ((M16 + 1) & 1) * BUFB;
      kbody<2, NSV, JBA>(M16 + 1, 0, R, bufc, Wa, Wb, cbBase, lr, acc);
      STEP_POST()
    }
  } else {
    const char* bufc = lds + (M16 & 1) * BUFB;
    kbody<2, NSV, JBA>(M16, 0, 16, bufc, Wa, Wb, cbBase, lr, acc);
    STEP_POST()
  }
#undef STEP_PRE
#undef STEP_POST

  // Epilogue: per-channel (lr) sum of y^2 over this wave's valid outputs.
  float esum = 0.0f;
#pragma unroll
  for (int g = 0; g < 2; ++g)
#pragma unroll
    for (int sj = 0; sj < 2; ++sj)
#pragma unroll
      for (int jb = 0; jb < JBA; ++jb) {
        int j = 8 * (t0 + jb) + 2 * q + sj;
#pragma unroll
        for (int r2 = 0; r2 < 4; ++r2) {
          int i = i0 + 16 * g + 4 * lg + r2;
          float v = acc[g][sj][jb][r2];
          esum += (i < HOUT && j < HOUT) ? v * v : 0.0f;
        }
      }
  esum += __shfl_xor(esum, 16, 64);
  esum += __shfl_xor(esum, 32, 64);
  if (lg == 0) atomicAdd(&E[SIDX * 256 + n * 16 + lr], esum);
}

// Dispatch: s3 [0,256) s2 [256,896) s1 [896,1344) s0 [1344,1856).
// Within a scale: bl&7 encodes the sigma-pair (XCD locality), rest = n/ig/ks.
__global__ __launch_bounds__(512, 4) void conv_mfma_kernel(
    const unsigned short* __restrict__ xb, const unsigned short* __restrict__ wq,
    float* __restrict__ E) {
  __shared__ char lds[2 * BUFB];
  int b = blockIdx.x;
  if (b < 256) {                                   // s3: K=193, ks 96+97
    int q = (b & 7) >> 1;
    int rest = ((b >> 3) << 1) | (b & 1);          // [0,64)
    int ks = rest & 1, ig = (rest >> 1) & 1, n = rest >> 2;
    if (ks == 0) conv_scale<96, 193, 7, 2, 4, 64, 3>(xb, wq + WQ3, E, lds, n, ig * 32, 0, q);
    else         conv_scale<97, 193, 7, 2, 4, 64, 3>(xb, wq + WQ3, E, lds, n, ig * 32, 96, q);
  } else if (b < 896) {                            // s2: K=97, ks 48+49
    int bl = b - 256;
    int q = (bl & 7) >> 1;
    int rest = ((bl >> 3) << 1) | (bl & 1);        // [0,160)
    int ks = rest & 1, r2 = rest >> 1;
    int ig = r2 % 5, n = r2 / 5;
    if (ks == 0) conv_scale<48, 97, 4, 4, 5, 160, 2>(xb, wq + WQ2, E, lds, n, ig * 32, 0, q);
    else         conv_scale<49, 97, 4, 4, 5, 160, 2>(xb, wq + WQ2, E, lds, n, ig * 32, 48, q);
  } else if (b < 1344) {                           // s1: K=49
    int bl = b - 896;
    int q = (bl & 7) >> 1;
    int rest = ((bl >> 3) << 1) | (bl & 1);        // [0,112)
    int ig = rest % 7, n = rest / 7;
    conv_scale<49, 49, 2, 4, 7, 208, 1>(xb, wq + WQ1, E, lds, n, ig * 32, 0, q);
  } else {                                         // s0: K=25
    int bl = b - 1344;
    int q = (bl & 7) >> 1;
    int rest = ((bl >> 3) << 1) | (bl & 1);        // [0,128)
    int ig = rest & 7, n = rest >> 3;
    conv_scale<25, 25, 1, 4, 8, 232, 0>(xb, wq + WQ0, E, lds, n, ig * 32, 0, q);
  }
}

__global__ void finalize_kernel(const float* __restrict__ E, float* __restrict__ out) {
  int idx = threadIdx.x;
  if (idx >= 512) return;
  int s = idx & 3, c = (idx >> 2) & 7, n = idx >> 5;
  float denom;
  if (s == 0)      denom = 53824.0f;    // 1*232^2
  else if (s == 1) denom = 86528.0f;    // 2*208^2
  else if (s == 2) denom = 102400.0f;   // 4*160^2
  else             denom = 32768.0f;    // 8*64^2
  out[idx] = (E[s * 256 + n * 16 + c] + E[s * 256 + n * 16 + c + 8]) / denom;
}

extern "C" void kernel_launch(void* const* d_in, const int* in_sizes, int n_in,
                              void* d_out, int out_size, void* d_ws, size_t ws_size,
                              hipStream_t stream) {
  const float* x = (const float*)d_in[0];
  const float* w[4] = {(const float*)d_in[1], (const float*)d_in[2],
                       (const float*)d_in[3], (const float*)d_in[4]};
  static const int Ks[4] = {25, 49, 97, 193};
  static const int NSVs[4] = {1, 2, 4, 7};
  static const unsigned wOff[4] = {WQ0, WQ1, WQ2, WQ3};

  char* wsb = (char*)d_ws;
  float* E = (float*)wsb;                                  // 4 KB
  __hip_bfloat16* xb = (__hip_bfloat16*)(wsb + 4096);      // 2 MB
  unsigned short* wq = (unsigned short*)(wsb + 4096 + (size_t)XB_ELEMS * 2);

  hipMemsetAsync(E, 0, 1024 * sizeof(float), stream);
  xconvert_kernel<<<(XB_ELEMS + 255) / 256, 256, 0, stream>>>(x, xb);
  for (int s = 0; s < 4; ++s) {
    int total = 8 * Ks[s] * NSVs[s] * 512;
    wpack_kernel<<<2048, 256, 0, stream>>>(w[s], wq + wOff[s], Ks[s], NSVs[s], total);
  }
  conv_mfma_kernel<<<1856, 512, 0, stream>>>((const unsigned short*)xb, wq, E);
  finalize_kernel<<<1, 512, 0, stream>>>(E, (float*)d_out);
}

// Round 5
// 511.806 us; speedup vs baseline: 1.1478x; 1.1478x over previous
//
#include <hip/hip_runtime.h>
#include <hip/hip_bf16.h>

typedef __attribute__((ext_vector_type(8))) short short8v;
typedef __attribute__((ext_vector_type(4))) float f32x4;

#define IMG 256
#define NIMG 16
#define XB_ELEMS (NIMG * IMG * IMG)

// packed-weight element offsets: per sigma stride = K*NSV*512 elems, 8 sigmas
#define WQ0 0u
#define WQ1 102400u        // + 8*25*1*512
#define WQ2 503808u       // + 8*49*2*512
#define WQ3 2093056u       // + 8*97*4*512
#define WQEND 7624704u     // + 8*193*7*512   (15.25 MB)

#define BUFB 16384         // one LDS buffer: 32 rows x 512 B

// ---------------------------------------------------------------------------
// Fused prep: x f32->bf16 convert, then all 4 scales' weight packing.
// wq[sig][u][sv][lane*8+e]; v = 32sv+8(lane>>4)+e - sig, zero outside [0,K).
// ---------------------------------------------------------------------------
__global__ void prep_kernel(const float* __restrict__ x,
                            const float* __restrict__ w0, const float* __restrict__ w1,
                            const float* __restrict__ w2, const float* __restrict__ w3,
                            __hip_bfloat16* __restrict__ xb,
                            unsigned short* __restrict__ wq) {
  int idx = blockIdx.x * blockDim.x + threadIdx.x;
  if (idx < XB_ELEMS) { xb[idx] = __float2bfloat16(x[idx]); return; }
  int t = idx - XB_ELEMS;
  if (t >= (int)WQEND) return;
  const float* w; int K, NSV, base;
  if (t < (int)WQ1)      { w = w0; K = 25;  NSV = 1; base = WQ0; }
  else if (t < (int)WQ2) { w = w1; K = 49;  NSV = 2; base = WQ1; }
  else if (t < (int)WQ3) { w = w2; K = 97;  NSV = 4; base = WQ2; }
  else                   { w = w3; K = 193; NSV = 7; base = WQ3; }
  int id2 = t - base;
  int e = id2 & 7, lane = (id2 >> 3) & 63, rest = id2 >> 9;
  int sv = rest % NSV; rest /= NSV;
  int u = rest % K, sig = rest / K;
  int o = lane & 15;
  int v = sv * 32 + (lane >> 4) * 8 + e - sig;
  float val = (v >= 0 && v < K) ? w[(o * K + u) * K + v] : 0.0f;
  __hip_bfloat16 h = __float2bfloat16(val);
  wq[t] = *(unsigned short*)&h;
}

// Inner body: compile-time g-mask (bit0 = row-group 0, bit1 = row-group 1).
template <int GM, int NSV, int JBA>
__device__ __forceinline__ void kbody(int c, int rb0, int rb1, const char* bufc,
                                      const unsigned short* __restrict__ Wa,
                                      const unsigned short* __restrict__ Wb,
                                      int cbBase, int lr, f32x4 (&acc)[2][2][JBA]) {
#pragma unroll 1
  for (int rbL = rb0; rbL < rb1; ++rbL) {
    const int rowLoc = rbL + lr;
    const char* rbase = bufc + rowLoc * 512;
    const int u0i = 16 * c + rbL;                 // u for g=0; g=1 uses u0i-16
#pragma unroll
    for (int sv = 0; sv < NSV; ++sv) {
      short8v a_[JBA];
#pragma unroll
      for (int jb = 0; jb < JBA; ++jb) {
        int cb = cbBase + 16 * jb + 64 * sv;
        int addr = (cb & ~127) + ((((cb >> 4) ^ rowLoc) & 7) << 4);
        a_[jb] = *(const short8v*)(rbase + addr);
      }
      if (GM & 1) {
        const int wo = (u0i * NSV + sv) * 512;
        short8v ba = *(const short8v*)(Wa + wo);
        short8v bb = *(const short8v*)(Wb + wo);
#pragma unroll
        for (int jb = 0; jb < JBA; ++jb) {
          acc[0][0][jb] = __builtin_amdgcn_mfma_f32_16x16x32_bf16(a_[jb], ba, acc[0][0][jb], 0, 0, 0);
          acc[0][1][jb] = __builtin_amdgcn_mfma_f32_16x16x32_bf16(a_[jb], bb, acc[0][1][jb], 0, 0, 0);
        }
      }
      if (GM & 2) {
        const int wo = ((u0i - 16) * NSV + sv) * 512;
        short8v ba = *(const short8v*)(Wa + wo);
        short8v bb = *(const short8v*)(Wb + wo);
#pragma unroll
        for (int jb = 0; jb < JBA; ++jb) {
          acc[1][0][jb] = __builtin_amdgcn_mfma_f32_16x16x32_bf16(a_[jb], ba, acc[1][0][jb], 0, 0, 0);
          acc[1][1][jb] = __builtin_amdgcn_mfma_f32_16x16x32_bf16(a_[jb], bb, acc[1][1][jb], 0, 0, 0);
        }
      }
    }
  }
}

// Per-scale conv+energy. G=2 row-groups, JSIG=2 sigmas (pair q), WC compute
// waves (JBA t-slots each, t-window base t0b), 8-WC producer waves stage LDS.
template <int KL, int KFULL, int NSV, int JBA, int WC, int HOUT, int SIDX>
__device__ __forceinline__ void conv_scale(const unsigned short* __restrict__ xb,
                                           const unsigned short* __restrict__ wq_s,
                                           float* __restrict__ E, char* lds,
                                           int n, int i0, int u0, int q, int t0b) {
  constexpr int M16 = KL >> 4, R = KL & 15;
  constexpr int NCH = M16 + (R ? 2 : 1);
  constexpr unsigned SSTRIDE = (unsigned)KFULL * NSV * 512;

  const int wv = threadIdx.x >> 6, lane = threadIdx.x & 63;
  const int lr = lane & 15, lg = lane >> 4;
  const bool isProd = (WC < 8) && (wv >= WC);
  const unsigned short* Xn = xb + ((unsigned)n << 16);
  const int rowG0 = i0 + u0;

  const unsigned short* Wa = wq_s + (unsigned)(2 * q) * SSTRIDE +
                             (unsigned)(u0 * NSV) * 512 + lane * 8;
  const unsigned short* Wb = Wa + SSTRIDE;

  // Stage 32 rows (16 KB, 16x 1KB loads) of chunk cn into buffer cn&1.
  // LDS dest linear; source col pre-swizzled: slot' = (slot&~7)|((slot^row)&7).
  auto stage = [&](int cn) {
    char* dst = lds + (cn & 1) * BUFB;
    constexpr int NSTG = (WC < 8) ? (8 - WC) : 8;
    const int sid = (WC < 8) ? (wv - WC) : wv;
    constexpr int M = (16 + NSTG - 1) / NSTG;
#pragma unroll
    for (int k2 = 0; k2 < M; ++k2) {
      int ib = sid + NSTG * k2;
      if (ib >= 16) ib = 0;                       // benign duplicate
      int P = ib * 1024 + lane * 16;
      int lrow = P >> 9;
      int slot = (P >> 4) & 31;
      int srcslot = (slot & ~7) | ((slot ^ lrow) & 7);
      int grow = rowG0 + cn * 16 + lrow;
      if (grow > 255) grow = 255;
      const unsigned short* gp = Xn + (grow << 8) + srcslot * 8;
      __builtin_amdgcn_global_load_lds(
          (const __attribute__((address_space(1))) unsigned int*)(const void*)gp,
          (__attribute__((address_space(3))) unsigned int*)(void*)(dst + P), 16, 0, 0);
    }
  };

  if (isProd) {
    stage(0);
    asm volatile("s_waitcnt vmcnt(0)" ::: "memory");
    __builtin_amdgcn_s_barrier();
    for (int c = 0; c < NCH; ++c) {
      if (c + 1 < NCH) {
        stage(c + 1);
        asm volatile("s_waitcnt vmcnt(0)" ::: "memory");
      }
      __builtin_amdgcn_s_barrier();
    }
    return;
  }

  f32x4 acc[2][2][JBA];
#pragma unroll
  for (int g = 0; g < 2; ++g)
#pragma unroll
    for (int sj = 0; sj < 2; ++sj)
#pragma unroll
      for (int jb = 0; jb < JBA; ++jb) acc[g][sj][jb] = (f32x4)(0.0f);

  const int t0 = t0b + wv * JBA;
  const int cbBase = 16 * t0 + 16 * lg;

  if (WC == 8) {                                   // no producers: stage ourselves
    stage(0);
    asm volatile("s_waitcnt vmcnt(0)" ::: "memory");
  }
  __builtin_amdgcn_s_barrier();

#define STEP_PRE(c)  if (WC == 8 && (c) + 1 < NCH) stage((c) + 1);
#define STEP_POST()  if (WC == 8) asm volatile("s_waitcnt vmcnt(0)" ::: "memory"); \
                     __builtin_amdgcn_s_barrier();

  {  // step 0: g0 only, full
    const char* bufc = lds;
    STEP_PRE(0)
    __builtin_amdgcn_s_setprio(1);
    kbody<1, NSV, JBA>(0, 0, 16, bufc, Wa, Wb, cbBase, lr, acc);
    __builtin_amdgcn_s_setprio(0);
    STEP_POST()
  }
#pragma unroll 1
  for (int c = 1; c < M16; ++c) {                  // steady: both groups
    const char* bufc = lds + (c & 1) * BUFB;
    STEP_PRE(c)
    __builtin_amdgcn_s_setprio(1);
    kbody<3, NSV, JBA>(c, 0, 16, bufc, Wa, Wb, cbBase, lr, acc);
    __builtin_amdgcn_s_setprio(0);
    STEP_POST()
  }
  if (R > 0) {
    {  // step M16: g0 partial (rbL<R), g1 full
      const char* bufc = lds + (M16 & 1) * BUFB;
      STEP_PRE(M16)
      __builtin_amdgcn_s_setprio(1);
      kbody<3, NSV, JBA>(M16, 0, R, bufc, Wa, Wb, cbBase, lr, acc);
      kbody<2, NSV, JBA>(M16, R, 16, bufc, Wa, Wb, cbBase, lr, acc);
      __builtin_amdgcn_s_setprio(0);
      STEP_POST()
    }
    {  // step M16+1: g1 partial
      const char* bufc = lds + ((M16 + 1) & 1) * BUFB;
      __builtin_amdgcn_s_setprio(1);
      kbody<2, NSV, JBA>(M16 + 1, 0, R, bufc, Wa, Wb, cbBase, lr, acc);
      __builtin_amdgcn_s_setprio(0);
      STEP_POST()
    }
  } else {
    const char* bufc = lds + (M16 & 1) * BUFB;
    __builtin_amdgcn_s_setprio(1);
    kbody<2, NSV, JBA>(M16, 0, 16, bufc, Wa, Wb, cbBase, lr, acc);
    __builtin_amdgcn_s_setprio(0);
    STEP_POST()
  }
#undef STEP_PRE
#undef STEP_POST

  // Epilogue: per-channel (lr) sum of y^2 over this wave's valid outputs.
  float esum = 0.0f;
#pragma unroll
  for (int g = 0; g < 2; ++g)
#pragma unroll
    for (int sj = 0; sj < 2; ++sj)
#pragma unroll
      for (int jb = 0; jb < JBA; ++jb) {
        int j = 8 * (t0 + jb) + 2 * q + sj;
#pragma unroll
        for (int r2 = 0; r2 < 4; ++r2) {
          int i = i0 + 16 * g + 4 * lg + r2;
          float v = acc[g][sj][jb][r2];
          esum += (i < HOUT && j < HOUT) ? v * v : 0.0f;
        }
      }
  esum += __shfl_xor(esum, 16, 64);
  esum += __shfl_xor(esum, 32, 64);
  if (lg == 0) atomicAdd(&E[SIDX * 256 + n * 16 + lr], esum);
}

// Dispatch: s3 [0,256) s2 [256,1536) s1 [1536,2432) s0 [2432,3456).
// Bases are multiples of 8 so bl&7 is stable -> sigma-pair q = (bl&7)>>1
// gives XCD-pair weight locality; bit0 folds into the job index.
__global__ __launch_bounds__(512, 4) void conv_mfma_kernel(
    const unsigned short* __restrict__ xb, const unsigned short* __restrict__ wq,
    float* __restrict__ E) {
  __shared__ char lds[2 * BUFB];
  int b = blockIdx.x;
  if (b < 256) {                                   // s3: K=193, ks 96+97, T=8
    int q = (b & 7) >> 1;
    int rest = ((b >> 3) << 1) | (b & 1);          // [0,64)
    int ks = rest & 1, ig = (rest >> 1) & 1, n = rest >> 2;
    if (ks == 0) conv_scale<96, 193, 7, 2, 4, 64, 3>(xb, wq + WQ3, E, lds, n, ig * 32, 0, q, 0);
    else         conv_scale<97, 193, 7, 2, 4, 64, 3>(xb, wq + WQ3, E, lds, n, ig * 32, 96, q, 0);
  } else if (b < 1536) {                           // s2: K=97, ks 48+49, T=20 (2x10)
    int bl = b - 256;
    int q = (bl & 7) >> 1;
    int rest = ((bl >> 3) << 1) | (bl & 1);        // [0,320)
    int ks = rest & 1, ts = (rest >> 1) & 1, r = rest >> 2;
    int ig = r % 5, n = r / 5;
    if (ks == 0) conv_scale<48, 97, 4, 2, 5, 160, 2>(xb, wq + WQ2, E, lds, n, ig * 32, 0, q, ts * 10);
    else         conv_scale<49, 97, 4, 2, 5, 160, 2>(xb, wq + WQ2, E, lds, n, ig * 32, 48, q, ts * 10);
  } else if (b < 2432) {                           // s1: K=49, T=26 (14+12)
    int bl = b - 1536;
    int q = (bl & 7) >> 1;
    int rest = ((bl >> 3) << 1) | (bl & 1);        // [0,224)
    int ts = rest & 1, r = rest >> 1;
    int ig = r % 7, n = r / 7;
    conv_scale<49, 49, 2, 2, 7, 208, 1>(xb, wq + WQ1, E, lds, n, ig * 32, 0, q, ts * 14);
  } else {                                         // s0: K=25, T=29 (16+13)
    int bl = b - 2432;
    int q = (bl & 7) >> 1;
    int rest = ((bl >> 3) << 1) | (bl & 1);        // [0,256)
    int ts = rest & 1, r = rest >> 1;
    int ig = r & 7, n = r >> 3;
    conv_scale<25, 25, 1, 2, 8, 232, 0>(xb, wq + WQ0, E, lds, n, ig * 32, 0, q, ts * 16);
  }
}

__global__ void finalize_kernel(const float* __restrict__ E, float* __restrict__ out) {
  int idx = threadIdx.x;
  if (idx >= 512) return;
  int s = idx & 3, c = (idx >> 2) & 7, n = idx >> 5;
  float denom;
  if (s == 0)      denom = 53824.0f;    // 1*232^2
  else if (s == 1) denom = 86528.0f;    // 2*208^2
  else if (s == 2) denom = 102400.0f;   // 4*160^2
  else             denom = 32768.0f;    // 8*64^2
  out[idx] = (E[s * 256 + n * 16 + c] + E[s * 256 + n * 16 + c + 8]) / denom;
}

extern "C" void kernel_launch(void* const* d_in, const int* in_sizes, int n_in,
                              void* d_out, int out_size, void* d_ws, size_t ws_size,
                              hipStream_t stream) {
  const float* x = (const float*)d_in[0];

  char* wsb = (char*)d_ws;
  float* E = (float*)wsb;                                  // 4 KB
  __hip_bfloat16* xb = (__hip_bfloat16*)(wsb + 4096);      // 2 MB
  unsigned short* wq = (unsigned short*)(wsb + 4096 + (size_t)XB_ELEMS * 2);

  hipMemsetAsync(E, 0, 1024 * sizeof(float), stream);
  int prepTotal = XB_ELEMS + (int)WQEND;
  prep_kernel<<<(prepTotal + 255) / 256, 256, 0, stream>>>(
      x, (const float*)d_in[1], (const float*)d_in[2], (const float*)d_in[3],
      (const float*)d_in[4], xb, wq);
  conv_mfma_kernel<<<3456, 512, 0, stream>>>((const unsigned short*)xb, wq, E);
  finalize_kernel<<<1, 512, 0, stream>>>(E, (float*)d_out);
}